// Round 5
// baseline (464.689 us; speedup 1.0000x reference)
//
#include <hip/hip_runtime.h>
#include <math.h>

// Problem constants (fixed by the reference).
#define BQ   16384
#define FQ   64
#define NBQ  64
#define HD   128
#define FG   4       // feature groups
#define FPG  16      // features per group
#define MT   128     // batch rows per block
#define NT   512     // threads (8 waves)

typedef __attribute__((ext_vector_type(8))) short s16x8;   // 8 bf16 (4 VGPRs)
typedef __attribute__((ext_vector_type(4))) float f32x4;   // MFMA C/D

// round-to-nearest-even fp32 -> bf16 (weight prep only)
__device__ __forceinline__ unsigned short f2bf(float x) {
    unsigned int u = __float_as_uint(x);
    return (unsigned short)((u + 0x7FFFu + ((u >> 16) & 1u)) >> 16);
}
// truncation fp32 -> bf16 (activations)
__device__ __forceinline__ unsigned short bftr(float x) {
    return (unsigned short)(__float_as_uint(x) >> 16);
}

__device__ __forceinline__ float softplus_stable(float v) {
    return (v > 0.0f) ? (v + log1pf(expf(-v))) : log1pf(expf(v));
}

// tanh-form gelu as sigmoid: gelu(v) = v / (1 + exp(-(1.5957691 v + 0.07135481 v^3)))
__device__ __forceinline__ f32x4 gelu4(f32x4 v) {
    const f32x4 v2 = v * v;
    const f32x4 tt = v2 * (-0.07135481f) + (-1.5957691f);
    const f32x4 s  = v * tt;
    f32x4 r;
    r[0] = __fdividef(v[0], 1.0f + __expf(s[0]));
    r[1] = __fdividef(v[1], 1.0f + __expf(s[1]));
    r[2] = __fdividef(v[2], 1.0f + __expf(s[2]));
    r[3] = __fdividef(v[3], 1.0f + __expf(s[3]));
    return r;
}

// sum across the 16 lanes of a DPP row — no LDS ops.
__device__ __forceinline__ float dppsum16(float x) {
    int t;
    t = __builtin_amdgcn_update_dpp(0, __float_as_int(x), 0xB1,  0xF, 0xF, true); // quad_perm [1,0,3,2]
    x += __int_as_float(t);
    t = __builtin_amdgcn_update_dpp(0, __float_as_int(x), 0x4E,  0xF, 0xF, true); // quad_perm [2,3,0,1]
    x += __int_as_float(t);
    t = __builtin_amdgcn_update_dpp(0, __float_as_int(x), 0x125, 0xF, 0xF, true); // row_ror:4
    x += __int_as_float(t);
    t = __builtin_amdgcn_update_dpp(0, __float_as_int(x), 0x129, 0xF, 0xF, true); // row_ror:8
    x += __int_as_float(t);
    return x;
}

// async 16B global->LDS
__device__ __forceinline__ void load16_lds(const unsigned short* g, unsigned short* l) {
    __builtin_amdgcn_global_load_lds(
        (const __attribute__((address_space(1))) unsigned int*)(uintptr_t)g,
        (__attribute__((address_space(3))) unsigned int*)(uintptr_t)l,
        16, 0, 0);
}

// h1g LDS addressing: stride 128 shorts, XOR swizzle to spread banks.
__device__ __forceinline__ int hofs(int row, int col) {
    return row * 128 + (col ^ (((row >> 2) & 3) << 4));
}

// ---------------- fused prep: swz (blocks 0..1023) | xtr (1024..1279) |
//                  misc (1280) | LN pack (1281..1312) ----------------
__global__ void __launch_bounds__(256) prep_all(
    const float* __restrict__ x,
    const float* __restrict__ att, const float* __restrict__ log_widths,
    const float* __restrict__ centers, const float* __restrict__ br,
    const float* __restrict__ bias,
    const float* __restrict__ W1, const float* __restrict__ Wr, const float* __restrict__ W2,
    const float* __restrict__ b1, const float* __restrict__ g1, const float* __restrict__ be1,
    const float* __restrict__ b2, const float* __restrict__ g2, const float* __restrict__ be2,
    unsigned short* __restrict__ W1s, unsigned short* __restrict__ Wrs,
    unsigned short* __restrict__ W2s,
    float* __restrict__ xT,
    float* __restrict__ wsoft, float* __restrict__ crw2, float* __restrict__ rbias,
    float* __restrict__ Pk)
{
    const int bid = blockIdx.x;
    const int t   = threadIdx.x;

    if (bid < 1024) {
        // ---- weight convert + swizzle into MFMA B-frag order ----
        const int gid = bid * 256 + t;
        const float* W; unsigned short* dst; int K, id;
        if (gid < 65536)       { W = W1; dst = W1s; K = 64;  id = gid; }
        else if (gid < 131072) { W = Wr; dst = Wrs; K = 64;  id = gid - 65536; }
        else                   { W = W2; dst = W2s; K = 128; id = gid - 131072; }
        const int KB = K >> 3;
        const int nn = id & 15;
        const int kb = (id >> 4) % KB;
        const int nt = ((id >> 4) / KB) & 7;
        const int f  = id / (KB * 16 * 8);
        const float* src = W + ((size_t)f * K + kb * 8) * HD + nt * 16 + nn;
        s16x8 o;
#pragma unroll
        for (int j = 0; j < 8; ++j) o[j] = (short)f2bf(src[(size_t)j * HD]);
        *(s16x8*)(dst + (size_t)f * K * HD + ((size_t)(nt * KB + kb) * 16 + nn) * 8) = o;
    } else if (bid < 1280) {
        // ---- LDS-tiled x transpose ----
        __shared__ float tile[64][65];
        const int b0 = (bid - 1024) * 64;
        {
            const int row = t & 63, cg = (t >> 6) * 16;
            const float4* src = (const float4*)(x + (size_t)(b0 + row) * FQ + cg);
#pragma unroll
            for (int i = 0; i < 4; ++i) {
                const float4 v = src[i];
                tile[row][cg + i * 4 + 0] = v.x;
                tile[row][cg + i * 4 + 1] = v.y;
                tile[row][cg + i * 4 + 2] = v.z;
                tile[row][cg + i * 4 + 3] = v.w;
            }
        }
        __syncthreads();
        {
            const int f = t >> 2, r0 = (t & 3) * 16;
            float* dst = xT + (size_t)f * BQ + b0 + r0;
#pragma unroll
            for (int i = 0; i < 16; ++i) dst[i] = tile[r0 + i][f];
        }
    } else if (bid == 1280) {
        // ---- softmax + rbf coeffs + folded head bias ----
        __shared__ float ws[64];
        if (t < 64) {
            float v = att[t];
            float m = v;
#pragma unroll
            for (int s = 32; s >= 1; s >>= 1) m = fmaxf(m, __shfl_xor(m, s, 64));
            float e = expf(v - m);
            float ssum = e;
#pragma unroll
            for (int s = 32; s >= 1; s >>= 1) ssum += __shfl_xor(ssum, s, 64);
            const float w = e / ssum;
            ws[t] = w;
            wsoft[t] = w;
        }
        __syncthreads();
        for (int i = t; i < FQ * NBQ; i += 256) {
            float lw = fminf(fmaxf(log_widths[i], -5.0f), 5.0f);
            const float rw = 1.0f / (expf(lw) + 0.1f);
            ((float2*)crw2)[i] = make_float2(rw, -centers[i] * rw);
        }
        if (t < HD) {
            float s = bias[t];
            for (int f = 0; f < FQ; ++f) s += 0.1f * ws[f] * br[f * HD + t];
            rbias[t] = s;
        }
    } else {
        // ---- pack LN params: Pk[(f*128+c)*8] = {b1,g1,be1,0, b2,g2,be2,0} ----
        const int id = (bid - 1281) * 256 + t;
        if (id < FQ * HD) {
            ((float4*)Pk)[id * 2]     = make_float4(b1[id], g1[id], be1[id], 0.0f);
            ((float4*)Pk)[id * 2 + 1] = make_float4(b2[id], g2[id], be2[id], 0.0f);
        }
    }
}

// ---------------- fused MFMA NAM body ----------------
// grid 512 = 4 fgroups x 128 row-tiles (M=128). 512 threads = 8 waves, 16 rows/wave.
// LDS 64 KB -> 2 blocks/CU. W1/Wr staged via register prefetch + ds_write
// (so no barrier waits on a freshly-issued DMA); W2 via async DMA under LN1.
__global__ void __launch_bounds__(NT, 4) nam_main(
    const float* __restrict__ crw2,
    const float* __restrict__ xT,
    const unsigned short* __restrict__ W1s,
    const unsigned short* __restrict__ Wrs,
    const unsigned short* __restrict__ W2s,
    const float* __restrict__ Pk,
    const float* __restrict__ wsoft,
    float* __restrict__ aggP)
{
    __shared__ __align__(16) unsigned short wbuf[16384];   // 32 KB: W1+Wr, then W2
    __shared__ __align__(16) unsigned short hbuf[16384];   // 32 KB: h1g (swizzled)

    const int t    = threadIdx.x;
    const int ln   = t & 63;
    const int wv   = t >> 6;        // wave 0..7
    const int n    = ln & 15;
    const int q    = ln >> 4;
    const int wrow = wv * 16;
    const int fg   = blockIdx.x & 3;
    const int rb   = blockIdx.x >> 2;     // 0..127
    const int b0   = rb * MT;

    f32x4 acc[8];
#pragma unroll
    for (int nt = 0; nt < 8; ++nt) acc[nt] = f32x4{0.f, 0.f, 0.f, 0.f};

    // ---- preamble: async DMA of the FIRST feature's W1+Wr ----
    {
        const int f0 = fg * FPG + (rb & (FPG - 1));
        const unsigned short* gw1 = W1s + (size_t)f0 * 8192;
        const unsigned short* gwr = Wrs + (size_t)f0 * 8192;
#pragma unroll
        for (int i = 0; i < 4; ++i) {
            const int chunk = i * 8 + wv;
            const unsigned short* src = (chunk < 16) ? (gw1 + chunk * 512)
                                                     : (gwr + (chunk - 16) * 512);
            load16_lds(src + ln * 8, wbuf + chunk * 512);
        }
    }

    int4 pf0, pf1, pf2, pf3;   // next-iter W1/Wr prefetch (32 KB block-wide)

    for (int ff = 0; ff < FPG; ++ff) {
        const int f = fg * FPG + ((ff + rb) & (FPG - 1));   // decorrelated order

        // ---- stage prefetched W1/Wr (iters >= 1); wbuf is free after last barrier ----
        if (ff > 0) {
            *(int4*)&wbuf[t * 8]         = pf0;
            *(int4*)&wbuf[4096 + t * 8]  = pf1;
            *(int4*)&wbuf[8192 + t * 8]  = pf2;
            *(int4*)&wbuf[12288 + t * 8] = pf3;
        }

        // ---- rbf A-fragments directly in registers ----
        s16x8 a0, a1;
        {
            float xv = xT[(size_t)f * BQ + b0 + wrow + n];
            xv = fminf(fmaxf(xv, -10.0f), 10.0f);
            const float4* c4 = ((const float4*)crw2) + f * 32;
            unsigned int p[8];
#pragma unroll
            for (int h = 0; h < 2; ++h) {
#pragma unroll
                for (int i = 0; i < 4; ++i) {
                    const float4 cc = c4[h * 16 + q * 4 + i];   // {rw,nc, rw,nc}
                    const float d0 = fmaf(xv, cc.x, cc.y);
                    const float d1 = fmaf(xv, cc.z, cc.w);
                    const float e0 = __expf(-0.5f * d0 * d0);
                    const float e1 = __expf(-0.5f * d1 * d1);
                    p[h * 4 + i] = __builtin_amdgcn_perm(__float_as_uint(e1),
                                                         __float_as_uint(e0), 0x07060302u);
                }
            }
            int4 pa = make_int4(p[0], p[1], p[2], p[3]);
            int4 pb = make_int4(p[4], p[5], p[6], p[7]);
            a0 = *(s16x8*)&pa;
            a1 = *(s16x8*)&pb;
        }
        const float wf   = wsoft[f];
        const float wf01 = 0.1f * wf;
        __syncthreads();   // B1: W1/Wr visible (iter0: DMA drain; else: ds_writes)

        // ---- prefetch NEXT iter's W1/Wr into registers (3K cyc before use) ----
        {
            const int f2 = fg * FPG + ((ff + 1 + rb) & (FPG - 1));
            const unsigned short* g1p = W1s + (size_t)f2 * 8192 + t * 8;
            const unsigned short* grp = Wrs + (size_t)f2 * 8192 + t * 8;
            pf0 = *(const int4*)(g1p);
            pf1 = *(const int4*)(g1p + 4096);
            pf2 = *(const int4*)(grp);
            pf3 = *(const int4*)(grp + 4096);
        }

        // ---- GEMM1 (hc) + GEMMr folded straight into acc ----
        f32x4 hc[8];
#pragma unroll
        for (int nt = 0; nt < 8; ++nt) {
            const s16x8 bA = *(const s16x8*)&wbuf[(nt * 8 + 0) * 128 + ln * 8];
            const s16x8 bB = *(const s16x8*)&wbuf[(nt * 8 + 4) * 128 + ln * 8];
            f32x4 z = f32x4{0.f, 0.f, 0.f, 0.f};
            z = __builtin_amdgcn_mfma_f32_16x16x32_bf16(a0, bA, z, 0, 0, 0);
            z = __builtin_amdgcn_mfma_f32_16x16x32_bf16(a1, bB, z, 0, 0, 0);
            hc[nt] = z;
            const s16x8 cA = *(const s16x8*)&wbuf[8192 + (nt * 8 + 0) * 128 + ln * 8];
            const s16x8 cB = *(const s16x8*)&wbuf[8192 + (nt * 8 + 4) * 128 + ln * 8];
            f32x4 y = f32x4{0.f, 0.f, 0.f, 0.f};
            y = __builtin_amdgcn_mfma_f32_16x16x32_bf16(a0, cA, y, 0, 0, 0);
            y = __builtin_amdgcn_mfma_f32_16x16x32_bf16(a1, cB, y, 0, 0, 0);
            acc[nt] = y * wf01 + acc[nt];
        }
        __syncthreads();   // B2: all waves done reading W1/Wr

        // ---- stage W2[f] (32 KB) async — overlaps LN1 VALU below ----
        {
            const unsigned short* gw2 = W2s + (size_t)f * 16384;
#pragma unroll
            for (int i = 0; i < 4; ++i) {
                const int chunk = i * 8 + wv;
                load16_lds(gw2 + chunk * 512 + ln * 8, wbuf + chunk * 512);
            }
        }

        // ---- LN1 (+b1), DPP reduce, gelu, h1g -> hbuf ----
        const size_t pkb = ((size_t)f * HD + n) * 8;
        f32x4 sm = {0.f, 0.f, 0.f, 0.f}, sq = {0.f, 0.f, 0.f, 0.f};
#pragma unroll
        for (int nt = 0; nt < 8; ++nt) {
            const float4 pA = *(const float4*)(Pk + pkb + nt * 128);
            const f32x4 v = hc[nt] + pA.x;
            hc[nt] = v; sm += v; sq += v * v;
        }
        f32x4 mu4, rs4;
#pragma unroll
        for (int i = 0; i < 4; ++i) {
            const float s  = dppsum16(sm[i]);
            const float qq = dppsum16(sq[i]);
            mu4[i] = s * (1.0f / 128.0f);
            const float var = qq * (1.0f / 128.0f) - mu4[i] * mu4[i];
            rs4[i] = rsqrtf(var + 1e-5f);
        }
#pragma unroll
        for (int nt = 0; nt < 8; ++nt) {
            const float4 pA = *(const float4*)(Pk + pkb + nt * 128);
            const f32x4 sg = rs4 * pA.y;
            const f32x4 c1 = -mu4 * sg + pA.z;
            const f32x4 z  = gelu4(hc[nt] * sg + c1);
#pragma unroll
            for (int i = 0; i < 4; ++i)
                hbuf[hofs(wrow + q * 4 + i, nt * 16 + n)] = bftr(z[i]);
        }
        __syncthreads();   // B3: W2 drained + h1g visible

        // ---- GEMM2: A = h1g frags (K=128); output reuses hc regs ----
        s16x8 A2[4];
#pragma unroll
        for (int c = 0; c < 4; ++c)
            A2[c] = *(const s16x8*)&hbuf[hofs(wrow + n, c * 32 + q * 8)];
#pragma unroll
        for (int nt = 0; nt < 8; ++nt) {
            f32x4 z = f32x4{0.f, 0.f, 0.f, 0.f};
#pragma unroll
            for (int c = 0; c < 4; ++c) {
                const s16x8 bF = *(const s16x8*)&wbuf[(nt * 16 + c * 4) * 128 + ln * 8];
                z = __builtin_amdgcn_mfma_f32_16x16x32_bf16(A2[c], bF, z, 0, 0, 0);
            }
            hc[nt] = z;
        }

        // ---- LN2 (+b2), gelu, attention weight into acc ----
        sm = f32x4{0.f, 0.f, 0.f, 0.f}; sq = f32x4{0.f, 0.f, 0.f, 0.f};
#pragma unroll
        for (int nt = 0; nt < 8; ++nt) {
            const float4 pB = *(const float4*)(Pk + pkb + nt * 128 + 4);
            const f32x4 v = hc[nt] + pB.x;
            hc[nt] = v; sm += v; sq += v * v;
        }
#pragma unroll
        for (int i = 0; i < 4; ++i) {
            const float s  = dppsum16(sm[i]);
            const float qq = dppsum16(sq[i]);
            mu4[i] = s * (1.0f / 128.0f);
            const float var = qq * (1.0f / 128.0f) - mu4[i] * mu4[i];
            rs4[i] = rsqrtf(var + 1e-5f);
        }
#pragma unroll
        for (int nt = 0; nt < 8; ++nt) {
            const float4 pB = *(const float4*)(Pk + pkb + nt * 128 + 4);
            const f32x4 sg = rs4 * pB.y;
            const f32x4 c1 = -mu4 * sg + pB.z;
            acc[nt] = gelu4(hc[nt] * sg + c1) * wf + acc[nt];
        }
        __syncthreads();   // B0: all waves done reading wbuf(W2)/hbuf
    }

    // ---- epilogue: plain stores into this fgroup's partial (no atomics) ----
    float* ap = aggP + ((size_t)fg * BQ + b0 + wrow + q * 4) * HD + n;
#pragma unroll
    for (int nt = 0; nt < 8; ++nt) {
#pragma unroll
        for (int i = 0; i < 4; ++i) {
            ap[(size_t)i * HD + nt * 16] = acc[nt][i];
        }
    }
}

// ---------------- mixture-beta head: one wave per batch row ----------------
__global__ void __launch_bounds__(256) nam_head(
    const float* __restrict__ aggP, const float* __restrict__ rbias,
    const float* __restrict__ Wpi, const float* __restrict__ bpi,
    const float* __restrict__ Wa,  const float* __restrict__ ba,
    const float* __restrict__ Wb,  const float* __restrict__ bb,
    float* __restrict__ out)
{
    const int gid  = blockIdx.x * blockDim.x + threadIdx.x;
    const int row  = gid >> 6;
    const int lane = threadIdx.x & 63;
    if (row >= BQ) return;

    const float2 p0 = ((const float2*)(aggP + (size_t)row * HD))[lane];
    const float2 p1 = ((const float2*)(aggP + ((size_t)BQ + row) * HD))[lane];
    const float2 p2 = ((const float2*)(aggP + ((size_t)2 * BQ + row) * HD))[lane];
    const float2 p3 = ((const float2*)(aggP + ((size_t)3 * BQ + row) * HD))[lane];
    const float2 rb = ((const float2*)rbias)[lane];
    const float ax = p0.x + p1.x + p2.x + p3.x + rb.x;
    const float ay = p0.y + p1.y + p2.y + p3.y + rb.y;

    const float2* wp = (const float2*)Wpi;
    const float2* wa = (const float2*)Wa;
    const float2* wb = (const float2*)Wb;
    const float2 p01 = wp[lane * 3], p23 = wp[lane * 3 + 1], p45 = wp[lane * 3 + 2];
    const float2 a01 = wa[lane * 3], a23 = wa[lane * 3 + 1], a45 = wa[lane * 3 + 2];
    const float2 b01 = wb[lane * 3], b23 = wb[lane * 3 + 1], b45 = wb[lane * 3 + 2];

    float ppi0 = ax * p01.x + ay * p23.y;
    float ppi1 = ax * p01.y + ay * p45.x;
    float ppi2 = ax * p23.x + ay * p45.y;
    float pa0  = ax * a01.x + ay * a23.y;
    float pa1  = ax * a01.y + ay * a45.x;
    float pa2  = ax * a23.x + ay * a45.y;
    float pb0  = ax * b01.x + ay * b23.y;
    float pb1  = ax * b01.y + ay * b45.x;
    float pb2  = ax * b23.x + ay * b45.y;

#pragma unroll
    for (int s = 32; s >= 1; s >>= 1) {
        ppi0 += __shfl_xor(ppi0, s, 64);
        ppi1 += __shfl_xor(ppi1, s, 64);
        ppi2 += __shfl_xor(ppi2, s, 64);
        pa0  += __shfl_xor(pa0,  s, 64);
        pa1  += __shfl_xor(pa1,  s, 64);
        pa2  += __shfl_xor(pa2,  s, 64);
        pb0  += __shfl_xor(pb0,  s, 64);
        pb1  += __shfl_xor(pb1,  s, 64);
        pb2  += __shfl_xor(pb2,  s, 64);
    }

    if (lane == 0) {
        const float z0 = ppi0 + bpi[0], z1 = ppi1 + bpi[1], z2 = ppi2 + bpi[2];
        const float mz = fmaxf(z0, fmaxf(z1, z2));
        const float e0 = expf(z0 - mz), e1 = expf(z1 - mz), e2 = expf(z2 - mz);
        const float es = e0 + e1 + e2;

        const float al0 = fminf(fmaxf(softplus_stable(pa0 + ba[0]) + 1.01f, 1.01f), 100.0f);
        const float al1 = fminf(fmaxf(softplus_stable(pa1 + ba[1]) + 1.01f, 1.01f), 100.0f);
        const float al2 = fminf(fmaxf(softplus_stable(pa2 + ba[2]) + 1.01f, 1.01f), 100.0f);
        const float bt0 = fminf(fmaxf(softplus_stable(pb0 + bb[0]) + 1.01f, 1.01f), 100.0f);
        const float bt1 = fminf(fmaxf(softplus_stable(pb1 + bb[1]) + 1.01f, 1.01f), 100.0f);
        const float bt2 = fminf(fmaxf(softplus_stable(pb2 + bb[2]) + 1.01f, 1.01f), 100.0f);

        const float pred = (e0 * (al0 / (al0 + bt0))
                          + e1 * (al1 / (al1 + bt1))
                          + e2 * (al2 / (al2 + bt2))) / es;
        out[row] = fminf(fmaxf(pred, 0.001f), 0.999f);
    }
}

extern "C" void kernel_launch(void* const* d_in, const int* in_sizes, int n_in,
                              void* d_out, int out_size, void* d_ws, size_t ws_size,
                              hipStream_t stream) {
    const float* x          = (const float*)d_in[0];
    const float* centers    = (const float*)d_in[1];
    const float* log_widths = (const float*)d_in[2];
    const float* W1   = (const float*)d_in[3];
    const float* b1   = (const float*)d_in[4];
    const float* g1   = (const float*)d_in[5];
    const float* be1  = (const float*)d_in[6];
    const float* W2   = (const float*)d_in[7];
    const float* b2   = (const float*)d_in[8];
    const float* g2   = (const float*)d_in[9];
    const float* be2  = (const float*)d_in[10];
    const float* Wr   = (const float*)d_in[11];
    const float* br   = (const float*)d_in[12];
    const float* att  = (const float*)d_in[13];
    const float* bias = (const float*)d_in[14];
    const float* Wpi  = (const float*)d_in[15];
    const float* bpi  = (const float*)d_in[16];
    const float* Wa   = (const float*)d_in[17];
    const float* ba   = (const float*)d_in[18];
    const float* Wb   = (const float*)d_in[19];
    const float* bb   = (const float*)d_in[20];

    // ---- workspace layout (byte offsets, 16B-aligned; top ≈ 40.3 MB) ----
    char* ws = (char*)d_ws;
    float*          wsoft = (float*)(ws + 0);          //   256 B
    float*          rbias = (float*)(ws + 1024);       //   512 B
    float*          crw2  = (float*)(ws + 8192);       //  32 KB (float2[4096])
    float*          Pk    = (float*)(ws + 65536);      // 256 KB
    float*          xT    = (float*)(ws + 327680);     //   4 MB
    unsigned short* W1s   = (unsigned short*)(ws + 4521984);   // 1 MB
    unsigned short* Wrs   = (unsigned short*)(ws + 5570560);   // 1 MB
    unsigned short* W2s   = (unsigned short*)(ws + 6619136);   // 2 MB
    float*          aggP  = (float*)(ws + 8716288);    //  32 MB (4 partials)

    prep_all<<<1313, 256, 0, stream>>>(x, att, log_widths, centers, br, bias,
                                       W1, Wr, W2, b1, g1, be1, b2, g2, be2,
                                       W1s, Wrs, W2s, xT, wsoft, crw2, rbias, Pk);

    nam_main<<<(BQ / MT) * FG, NT, 0, stream>>>(crw2, xT, W1s, Wrs, W2s, Pk,
                                                wsoft, aggP);

    nam_head<<<BQ / 4, 256, 0, stream>>>(aggP, rbias, Wpi, bpi, Wa, ba, Wb, bb,
                                         (float*)d_out);
}